// Round 1
// baseline (356.056 us; speedup 1.0000x reference)
//
#include <hip/hip_runtime.h>

typedef __attribute__((ext_vector_type(8))) short s16x8;
typedef __attribute__((ext_vector_type(4))) float f32x4;

#define DEV static __device__ __forceinline__

// async global->LDS, 16B per lane. LDS dest must be uniform base + lane*16.
DEV void gload_lds16(const void* g, void* l) {
  __builtin_amdgcn_global_load_lds(
      (const __attribute__((address_space(1))) void*)g,
      (__attribute__((address_space(3))) void*)l, 16, 0, 0);
}

DEV unsigned short f2bf(float f) {  // RNE float->bf16 (no NaN inputs here)
  unsigned int u = __float_as_uint(f);
  u = (u + 0x7fffu + ((u >> 16) & 1u)) >> 16;
  return (unsigned short)u;
}

// ---------------- fp32 -> bf16 conversion ----------------
DEV void cvt8(const float* __restrict__ in, unsigned short* __restrict__ out, int i) {
  float4 a = *(const float4*)(in + i);
  float4 b = *(const float4*)(in + i + 4);
  union { s16x8 v; unsigned short u[8]; } o;
  o.u[0] = f2bf(a.x); o.u[1] = f2bf(a.y); o.u[2] = f2bf(a.z); o.u[3] = f2bf(a.w);
  o.u[4] = f2bf(b.x); o.u[5] = f2bf(b.y); o.u[6] = f2bf(b.z); o.u[7] = f2bf(b.w);
  *(s16x8*)(out + i) = o.v;
}

__global__ __launch_bounds__(256) void k_cvt(const float* __restrict__ in,
                                             unsigned short* __restrict__ out) {
  cvt8(in, out, (blockIdx.x * 256 + threadIdx.x) * 8);
}

__global__ __launch_bounds__(256) void k_cvt4(
    const float* __restrict__ a0, const float* __restrict__ a1,
    const float* __restrict__ a2, const float* __restrict__ a3,
    unsigned short* __restrict__ o0, unsigned short* __restrict__ o1,
    unsigned short* __restrict__ o2, unsigned short* __restrict__ o3) {
  const float* in; unsigned short* out;
  switch (blockIdx.y) {
    case 0: in = a0; out = o0; break;
    case 1: in = a1; out = o1; break;
    case 2: in = a2; out = o2; break;
    default: in = a3; out = o3; break;
  }
  cvt8(in, out, (blockIdx.x * 256 + threadIdx.x) * 8);
}

// ---------------- NT GEMM: C[M,N] = A[M,K] * W[N,K]^T + bias ----------------
// MODE 0: bf16 out, QKV head-split layout [B,H,S,dk]; MODE 1: fp32 out row-major.
// 128x128 tile, BK=64, 256 threads (2x2 waves of 64x64), K=1024.
// LDS rows are 64 bf16 (128B = 8 chunks of 16B); chunk XOR (row&7) swizzle applied
// on the GLOBAL source (global_load_lds writes linearly) and on the LDS read.
template <int MODE>
__global__ __launch_bounds__(256) void k_gemm(
    const unsigned short* __restrict__ A,
    const unsigned short* __restrict__ B0, const unsigned short* __restrict__ B1,
    const unsigned short* __restrict__ B2,
    const float* __restrict__ bias0, const float* __restrict__ bias1,
    const float* __restrict__ bias2,
    void* __restrict__ out0, void* __restrict__ out1, void* __restrict__ out2) {
  constexpr int K = 1024;
  __shared__ unsigned short As[128 * 64];
  __shared__ unsigned short Bs[128 * 64];

  const int z = blockIdx.z;
  const unsigned short* Bw = (z == 0) ? B0 : (z == 1) ? B1 : B2;
  const float* bias = (z == 0) ? bias0 : (z == 1) ? bias1 : bias2;
  void* outp = (z == 0) ? out0 : (z == 1) ? out1 : out2;

  const int tid = threadIdx.x;
  const int lane = tid & 63;
  const int l15 = lane & 15, g = lane >> 4;
  const int w = tid >> 6;
  const int wr = w >> 1, wc = w & 1;
  const int m0 = blockIdx.y * 128;
  const int n0 = blockIdx.x * 128;

  const int sr = tid >> 3;  // staging row-in-issue 0..31
  const int sc = tid & 7;   // staging chunk 0..7

  f32x4 acc[4][4] = {};

  for (int kt = 0; kt < K / 64; ++kt) {
#pragma unroll
    for (int i = 0; i < 4; ++i) {
      const int row = i * 32 + sr;
      gload_lds16(A + (size_t)(m0 + row) * K + kt * 64 + ((sc ^ (row & 7)) * 8),
                  (void*)(As + i * 2048 + tid * 8));
      gload_lds16(Bw + (size_t)(n0 + row) * K + kt * 64 + ((sc ^ (row & 7)) * 8),
                  (void*)(Bs + i * 2048 + tid * 8));
    }
    __syncthreads();
#pragma unroll
    for (int ks = 0; ks < 2; ++ks) {
      s16x8 af[4], bf[4];
#pragma unroll
      for (int i = 0; i < 4; ++i) {
        const int ra = wr * 64 + i * 16 + l15;
        af[i] = *(const s16x8*)(As + ra * 64 + (((ks * 4 + g) ^ (ra & 7)) * 8));
        const int rb = wc * 64 + i * 16 + l15;
        bf[i] = *(const s16x8*)(Bs + rb * 64 + (((ks * 4 + g) ^ (rb & 7)) * 8));
      }
#pragma unroll
      for (int i = 0; i < 4; ++i)
#pragma unroll
        for (int j = 0; j < 4; ++j)
          acc[i][j] = __builtin_amdgcn_mfma_f32_16x16x32_bf16(af[i], bf[j], acc[i][j], 0, 0, 0);
    }
    __syncthreads();
  }

  // epilogue: bias + store. C/D frag: col = lane&15, row = (lane>>4)*4 + reg.
#pragma unroll
  for (int j = 0; j < 4; ++j) {
    const int gcol = n0 + wc * 64 + j * 16 + l15;
    const float bv = bias[gcol];
#pragma unroll
    for (int i = 0; i < 4; ++i) {
#pragma unroll
      for (int r = 0; r < 4; ++r) {
        const int grow = m0 + wr * 64 + i * 16 + g * 4 + r;
        const float val = acc[i][j][r] + bv;
        if (MODE == 0) {
          const int bb = grow >> 11, s = grow & 2047;
          const int h = gcol >> 6, d = gcol & 63;
          ((unsigned short*)outp)[(((size_t)(bb * 16 + h) * 2048 + s) << 6) + d] = f2bf(val);
        } else {
          ((float*)outp)[(size_t)grow * 1024 + gcol] = val;
        }
      }
    }
  }
}

// ---------------- V transpose: [B,H,S,dk] -> [B,H,dk,S] ----------------
__global__ __launch_bounds__(256) void k_transpose(const unsigned short* __restrict__ v,
                                                   unsigned short* __restrict__ vt) {
  __shared__ unsigned short T[64 * 72];
  const int t = threadIdx.x;
  const size_t base = (size_t)(blockIdx.z * 16 + blockIdx.y) * 2048 * 64;
  const int s0 = blockIdx.x * 64;
  {
    const int srow = t >> 2, dc = (t & 3) * 16;
    const unsigned short* src = v + base + (size_t)(s0 + srow) * 64 + dc;
    *(s16x8*)(T + srow * 72 + dc) = *(const s16x8*)src;
    *(s16x8*)(T + srow * 72 + dc + 8) = *(const s16x8*)(src + 8);
  }
  __syncthreads();
  {
    const int drow = t >> 2, scc = (t & 3) * 16;
    union { s16x8 v8; unsigned short u[8]; } o0, o1;
#pragma unroll
    for (int e = 0; e < 8; ++e) o0.u[e] = T[(scc + e) * 72 + drow];
#pragma unroll
    for (int e = 0; e < 8; ++e) o1.u[e] = T[(scc + 8 + e) * 72 + drow];
    unsigned short* dst = vt + base + (size_t)drow * 2048 + s0 + scc;
    *(s16x8*)dst = o0.v8;
    *(s16x8*)(dst + 8) = o1.v8;
  }
}

// ---------------- flash attention ----------------
// grid (H=16, S/64=32, B=4), 256 threads = 4 waves, each wave owns 16 q-rows.
// KV tile = 64. K and Vt staged via global_load_lds with chunk^(row&7) swizzle.
__global__ __launch_bounds__(256) void k_attn(
    const unsigned short* __restrict__ q, const unsigned short* __restrict__ k,
    const unsigned short* __restrict__ vt, const float* __restrict__ mask,
    unsigned short* __restrict__ concat) {
  __shared__ unsigned short Ks[64 * 64];
  __shared__ unsigned short Vts[64 * 64];
  __shared__ unsigned short Ps[4 * 16 * 64];

  const int tid = threadIdx.x;
  const int lane = tid & 63;
  const int w = tid >> 6;
  const int l15 = lane & 15, g = lane >> 4;
  const int h = blockIdx.x, qt = blockIdx.y, b = blockIdx.z;

  const size_t bh = (size_t)(b * 16 + h) * 2048 * 64;
  const unsigned short* qb = q + bh;
  const unsigned short* kb = k + bh;
  const unsigned short* vb = vt + bh;
  const float* mb = mask + (size_t)b * 2048 * 2048;

  const int q0 = qt * 64 + w * 16;

  s16x8 qf[2];
  {
    const unsigned short* qr = qb + (size_t)(q0 + l15) * 64 + g * 8;
    qf[0] = *(const s16x8*)qr;
    qf[1] = *(const s16x8*)(qr + 32);
  }

  float m_r[4], l_r[4];
#pragma unroll
  for (int j = 0; j < 4; ++j) { m_r[j] = -1e30f; l_r[j] = 0.f; }
  f32x4 oacc[4] = {};

  const int sr = tid >> 3, sc = tid & 7;

  for (int t = 0; t < 32; ++t) {
    const int kv0 = t * 64;
#pragma unroll
    for (int i = 0; i < 2; ++i) {
      const int row = i * 32 + sr;
      gload_lds16(kb + (size_t)(kv0 + row) * 64 + ((sc ^ (row & 7)) * 8),
                  (void*)(Ks + i * 2048 + tid * 8));
      gload_lds16(vb + (size_t)row * 2048 + kv0 + ((sc ^ (row & 7)) * 8),
                  (void*)(Vts + i * 2048 + tid * 8));
    }
    __syncthreads();

    // S = Q K^T : A = Q (row=lane&15), B = K^T (col=lane&15 -> K row)
    f32x4 s[4];
#pragma unroll
    for (int f = 0; f < 4; ++f) {
      f32x4 a = {};
#pragma unroll
      for (int ks = 0; ks < 2; ++ks) {
        const int rk = f * 16 + l15;
        const s16x8 kf = *(const s16x8*)(Ks + rk * 64 + (((ks * 4 + g) ^ (rk & 7)) * 8));
        a = __builtin_amdgcn_mfma_f32_16x16x32_bf16(qf[ks], kf, a, 0, 0, 0);
      }
      s[f] = a;
    }
    // scale by 1/sqrt(dk) and multiplicative mask (fp32)
#pragma unroll
    for (int f = 0; f < 4; ++f)
#pragma unroll
      for (int j = 0; j < 4; ++j) {
        const int qrow = q0 + g * 4 + j;
        const int kvc = kv0 + f * 16 + l15;
        s[f][j] = s[f][j] * 0.125f * mb[(size_t)qrow * 2048 + kvc];
      }
    // online softmax (row stats replicated over each 16-lane group)
    float mnew[4], rs[4];
#pragma unroll
    for (int j = 0; j < 4; ++j) {
      float tm = fmaxf(fmaxf(s[0][j], s[1][j]), fmaxf(s[2][j], s[3][j]));
      tm = fmaxf(tm, __shfl_xor(tm, 1, 16));
      tm = fmaxf(tm, __shfl_xor(tm, 2, 16));
      tm = fmaxf(tm, __shfl_xor(tm, 4, 16));
      tm = fmaxf(tm, __shfl_xor(tm, 8, 16));
      mnew[j] = fmaxf(m_r[j], tm);
      rs[j] = __expf(m_r[j] - mnew[j]);
      m_r[j] = mnew[j];
    }
#pragma unroll
    for (int f = 0; f < 4; ++f)
#pragma unroll
      for (int j = 0; j < 4; ++j) s[f][j] = __expf(s[f][j] - mnew[j]);
#pragma unroll
    for (int j = 0; j < 4; ++j) {
      float ts = s[0][j] + s[1][j] + s[2][j] + s[3][j];
      ts += __shfl_xor(ts, 1, 16);
      ts += __shfl_xor(ts, 2, 16);
      ts += __shfl_xor(ts, 4, 16);
      ts += __shfl_xor(ts, 8, 16);
      l_r[j] = l_r[j] * rs[j] + ts;
#pragma unroll
      for (int c = 0; c < 4; ++c) oacc[c][j] *= rs[j];
    }
    // P -> wave-private LDS (bf16, swizzled), then PV
    unsigned short* pw = Ps + w * 1024;
#pragma unroll
    for (int f = 0; f < 4; ++f)
#pragma unroll
      for (int j = 0; j < 4; ++j) {
        const int qrl = g * 4 + j;
        const int col = f * 16 + l15;
        pw[qrl * 64 + (((col >> 3) ^ (qrl & 7)) * 8) + (col & 7)] = f2bf(s[f][j]);
      }
    asm volatile("s_waitcnt lgkmcnt(0)" ::: "memory");  // in-wave DS RAW fence
#pragma unroll
    for (int ks = 0; ks < 2; ++ks) {
      const s16x8 pa = *(const s16x8*)(pw + l15 * 64 + (((ks * 4 + g) ^ (l15 & 7)) * 8));
#pragma unroll
      for (int c = 0; c < 4; ++c) {
        const int rv = c * 16 + l15;
        const s16x8 vf = *(const s16x8*)(Vts + rv * 64 + (((ks * 4 + g) ^ (rv & 7)) * 8));
        oacc[c] = __builtin_amdgcn_mfma_f32_16x16x32_bf16(pa, vf, oacc[c], 0, 0, 0);
      }
    }
    __syncthreads();  // protect Ks/Vts before next stage
  }

  // normalize + write concat [B,S,H*dk] bf16
#pragma unroll
  for (int c = 0; c < 4; ++c)
#pragma unroll
    for (int j = 0; j < 4; ++j) {
      const int qrow = q0 + g * 4 + j;
      const int dcol = h * 64 + c * 16 + l15;
      concat[((size_t)(b * 2048) + qrow) * 1024 + dcol] = f2bf(oacc[c][j] / l_r[j]);
    }
}

// ---------------- launch ----------------
extern "C" void kernel_launch(void* const* d_in, const int* in_sizes, int n_in,
                              void* d_out, int out_size, void* d_ws, size_t ws_size,
                              hipStream_t stream) {
  const float* x    = (const float*)d_in[0];
  const float* mask = (const float*)d_in[1];
  const float* Wq   = (const float*)d_in[2];
  const float* bq   = (const float*)d_in[3];
  const float* Wk   = (const float*)d_in[4];
  const float* bk   = (const float*)d_in[5];
  const float* Wv   = (const float*)d_in[6];
  const float* bv   = (const float*)d_in[7];
  const float* Wo   = (const float*)d_in[8];
  const float* bo   = (const float*)d_in[9];

  char* ws = (char*)d_ws;
  unsigned short* xb  = (unsigned short*)(ws);                        // 16 MB (x bf16; later aliased by concat)
  unsigned short* wqb = (unsigned short*)(ws + (size_t)16777216);     // 2 MB each
  unsigned short* wkb = (unsigned short*)(ws + (size_t)18874368);
  unsigned short* wvb = (unsigned short*)(ws + (size_t)20971520);
  unsigned short* wob = (unsigned short*)(ws + (size_t)23068672);
  unsigned short* qw  = (unsigned short*)(ws + (size_t)25165824);     // 16 MB each
  unsigned short* kw  = (unsigned short*)(ws + (size_t)41943040);
  unsigned short* vw  = (unsigned short*)(ws + (size_t)58720256);
  unsigned short* vtw = (unsigned short*)(ws + (size_t)75497472);     // ends at 92274688
  unsigned short* cw  = xb;  // concat aliases x_bf16 (dead after QKV GEMMs)

  // 1) conversions
  k_cvt<<<dim3(4096), dim3(256), 0, stream>>>(x, xb);
  k_cvt4<<<dim3(512, 4), dim3(256), 0, stream>>>(Wq, Wk, Wv, Wo, wqb, wkb, wvb, wob);
  // 2) QKV projections -> [B,H,S,dk] bf16
  k_gemm<0><<<dim3(8, 64, 3), dim3(256), 0, stream>>>(xb, wqb, wkb, wvb, bq, bk, bv,
                                                      (void*)qw, (void*)kw, (void*)vw);
  // 3) V -> V^T [B,H,dk,S]
  k_transpose<<<dim3(32, 16, 4), dim3(256), 0, stream>>>(vw, vtw);
  // 4) flash attention -> concat bf16 [B,S,1024]
  k_attn<<<dim3(16, 32, 4), dim3(256), 0, stream>>>(qw, kw, vtw, mask, cw);
  // 5) output projection -> fp32 d_out
  k_gemm<1><<<dim3(8, 64, 1), dim3(256), 0, stream>>>(cw, wob, wob, wob, bo, bo, bo,
                                                      d_out, d_out, d_out);
}